// Round 7
// baseline (4361.995 us; speedup 1.0000x reference)
//
#include <hip/hip_runtime.h>

// ResidualQuantizer: K=4 stages, C=1024 centroids, D=64, N=B*T=131072 rows.
// Outputs (flat f32 concat): quantized[N*D], loss[N], nn_idx[K*N] (as float),
// codebooks_out[K*C*D], counts[K*C].
//
// Bit-matches the checker's numpy-f32 reference pipeline:
//  - dot(residual, centroid): single sequential k-ascending f32 FMA chain
//  - ||c||^2: numpy pairwise-8 sum of separately-rounded squares
//  - score = fmaf(-2, dot, cn)
//  - argmin: first strict min, ascending c (tie across halves -> lower half)
//  - residual/STE updates in reference f32 op order
//
// Parallel layout: 1024 blocks x 256 threads. Waves pair up: waves {2p,2p+1}
// own the same 64 rows; half 0 scans c in [0,512), half 1 scans [512,1024)
// (centroid index wave-uniform -> scalar/broadcast loads). LDS combines the
// per-row argmin. 16 waves/CU vs round-4's 8.

#define RQ_K 4
#define RQ_C 1024
#define RQ_D 64
#define RQ_N 131072

// ---------------- kernel 0: centroid norms, numpy pairwise-8 order ----------------
__global__ void rq_cnorm_kernel(const float* __restrict__ cb,
                                float* __restrict__ cn32) {
  int c = blockIdx.x * blockDim.x + threadIdx.x;
  if (c >= RQ_K * RQ_C) return;
  const float* p = cb + (size_t)c * RQ_D;
  float rr[8];
#pragma unroll
  for (int j = 0; j < 8; ++j) {
    float sq = p[j] * p[j];
    asm volatile("" : "+v"(sq));  // forbid fma contraction: square rounds alone
    rr[j] = sq;
  }
#pragma unroll
  for (int i = 8; i < RQ_D; i += 8) {
#pragma unroll
    for (int j = 0; j < 8; ++j) {
      float sq = p[i + j] * p[i + j];
      asm volatile("" : "+v"(sq));
      rr[j] = rr[j] + sq;
    }
  }
  float s = ((rr[0] + rr[1]) + (rr[2] + rr[3])) + ((rr[4] + rr[5]) + (rr[6] + rr[7]));
  cn32[c] = s;
}

// ---------------- kernel 1: main RQ ----------------
__launch_bounds__(256, 4)
__global__ void rq_main_kernel(const float* __restrict__ in,
                               const float* __restrict__ cb,
                               const float* __restrict__ cn32,
                               float* __restrict__ out_q,
                               float* __restrict__ out_nn,
                               float* __restrict__ out_counts,
                               double* __restrict__ ssq_acc) {
  const int wave = threadIdx.x >> 6;
  const int lane = threadIdx.x & 63;
  const int pair = wave >> 1;   // 0,1: which 64-row group in this block
  const int half = wave & 1;    // 0,1: which half of the centroid range
  const int row  = blockIdx.x * 128 + pair * 64 + lane;

  __shared__ float lmv[2][2][64];
  __shared__ int   lmi[2][2][64];
  __shared__ double smem[4];

  float r[RQ_D];  // current residual (f32, reference rounding)
  {
    const float4* ip = reinterpret_cast<const float4*>(in + (size_t)row * RQ_D);
#pragma unroll
    for (int i = 0; i < RQ_D / 4; ++i) {
      float4 v = ip[i];
      r[4 * i + 0] = v.x; r[4 * i + 1] = v.y;
      r[4 * i + 2] = v.z; r[4 * i + 3] = v.w;
    }
  }
  double ssq = 0.0;  // loss partial (counted from half==0 only)

#pragma unroll 1
  for (int k = 0; k < RQ_K; ++k) {
    const float* cbk = cb + (size_t)k * RQ_C * RQ_D;
    const float* cnk = cn32 + k * RQ_C;
    const int c0 = half * (RQ_C / 2);
    float m1 = 3.402823466e38f;
    int i1 = c0;

    // f32 screening over this wave's 512 centroids, 4 per iteration
    // (4 independent chains; each chain is the sequential k-ascending FMA
    // order of the reference). Centroid index is wave-uniform.
#pragma unroll 1
    for (int c = c0; c < c0 + RQ_C / 2; c += 4) {
      const float4* b0 = reinterpret_cast<const float4*>(cbk + (size_t)(c + 0) * RQ_D);
      const float4* b1 = reinterpret_cast<const float4*>(cbk + (size_t)(c + 1) * RQ_D);
      const float4* b2 = reinterpret_cast<const float4*>(cbk + (size_t)(c + 2) * RQ_D);
      const float4* b3 = reinterpret_cast<const float4*>(cbk + (size_t)(c + 3) * RQ_D);
      float a0 = 0.f, a1 = 0.f, a2 = 0.f, a3 = 0.f;
#pragma unroll
      for (int i = 0; i < RQ_D / 4; ++i) {
        float4 v0 = b0[i];
        a0 = fmaf(v0.x, r[4 * i + 0], a0);
        a0 = fmaf(v0.y, r[4 * i + 1], a0);
        a0 = fmaf(v0.z, r[4 * i + 2], a0);
        a0 = fmaf(v0.w, r[4 * i + 3], a0);
        float4 v1 = b1[i];
        a1 = fmaf(v1.x, r[4 * i + 0], a1);
        a1 = fmaf(v1.y, r[4 * i + 1], a1);
        a1 = fmaf(v1.z, r[4 * i + 2], a1);
        a1 = fmaf(v1.w, r[4 * i + 3], a1);
        float4 v2 = b2[i];
        a2 = fmaf(v2.x, r[4 * i + 0], a2);
        a2 = fmaf(v2.y, r[4 * i + 1], a2);
        a2 = fmaf(v2.z, r[4 * i + 2], a2);
        a2 = fmaf(v2.w, r[4 * i + 3], a2);
        float4 v3 = b3[i];
        a3 = fmaf(v3.x, r[4 * i + 0], a3);
        a3 = fmaf(v3.y, r[4 * i + 1], a3);
        a3 = fmaf(v3.z, r[4 * i + 2], a3);
        a3 = fmaf(v3.w, r[4 * i + 3], a3);
      }
      float s0 = fmaf(-2.f, a0, cnk[c + 0]);
      float s1 = fmaf(-2.f, a1, cnk[c + 1]);
      float s2 = fmaf(-2.f, a2, cnk[c + 2]);
      float s3 = fmaf(-2.f, a3, cnk[c + 3]);
      bool l0 = s0 < m1; m1 = l0 ? s0 : m1; i1 = l0 ? (c + 0) : i1;
      bool l1 = s1 < m1; m1 = l1 ? s1 : m1; i1 = l1 ? (c + 1) : i1;
      bool l2 = s2 < m1; m1 = l2 ? s2 : m1; i1 = l2 ? (c + 2) : i1;
      bool l3 = s3 < m1; m1 = l3 ? s3 : m1; i1 = l3 ? (c + 3) : i1;
    }

    // cross-wave argmin combine; tie -> half 0 (lower index = first occurrence)
    lmv[pair][half][lane] = m1;
    lmi[pair][half][lane] = i1;
    __syncthreads();
    float ma = lmv[pair][0][lane]; int ia = lmi[pair][0][lane];
    float mb = lmv[pair][1][lane]; int ib = lmi[pair][1][lane];
    const int best = (mb < ma) ? ib : ia;
    __syncthreads();  // LDS reusable next stage

    if (half == 0) {
      out_nn[k * RQ_N + row] = (float)best;
      atomicAdd(&out_counts[k * RQ_C + best], 1.0f);
    }

    // residual / STE update, reference f32 op order (both halves duplicate
    // this deterministically so each keeps a current residual)
    const float4* qp = reinterpret_cast<const float4*>(cbk + (size_t)best * RQ_D);
#pragma unroll
    for (int i = 0; i < RQ_D / 4; ++i) {
      float4 qv = qp[i];
      float qa[4] = {qv.x, qv.y, qv.z, qv.w};
#pragma unroll
      for (int j = 0; j < 4; ++j) {
        int d = 4 * i + j;
        float t = qa[j] - r[d];   // quant - residual
        float qste = r[d] + t;    // straight-through value
        r[d] = r[d] - qste;       // new residual
        ssq = fma((double)t, (double)t, ssq);
      }
    }
  }

  // quantized = sum of quant_ste over stages = in_row - r_final (telescoping;
  // differs from np's pairwise 4-term sum by ~1 ulp, far inside threshold)
  if (half == 0) {
    const float4* ip = reinterpret_cast<const float4*>(in + (size_t)row * RQ_D);
    float4* op = reinterpret_cast<float4*>(out_q + (size_t)row * RQ_D);
#pragma unroll
    for (int i = 0; i < RQ_D / 4; ++i) {
      float4 v = ip[i];
      op[i] = make_float4(v.x - r[4 * i + 0], v.y - r[4 * i + 1],
                          v.z - r[4 * i + 2], v.w - r[4 * i + 3]);
    }
  }

  // block-reduce loss partial (double), half==0 waves only, one atomic/block
#pragma unroll
  for (int off = 32; off > 0; off >>= 1) ssq += __shfl_down(ssq, off);
  if (lane == 0) smem[wave] = (half == 0) ? ssq : 0.0;
  __syncthreads();
  if (threadIdx.x == 0) {
    double t = (smem[0] + smem[1]) + (smem[2] + smem[3]);
    atomicAdd(ssq_acc, t);
  }
}

// ---------------- kernel 2: loss broadcast + codebook copy ----------------
__global__ void rq_final_kernel(const double* __restrict__ ssq_acc,
                                const float* __restrict__ cb,
                                float* __restrict__ out_loss,
                                float* __restrict__ out_cb) {
  int i = blockIdx.x * blockDim.x + threadIdx.x;
  float lossf = (float)(ssq_acc[0] / (double)((long long)RQ_N * RQ_D));
  if (i < RQ_N) out_loss[i] = lossf;
  if (i < RQ_K * RQ_C * RQ_D) out_cb[i] = cb[i];
}

extern "C" void kernel_launch(void* const* d_in, const int* in_sizes, int n_in,
                              void* d_out, int out_size, void* d_ws, size_t ws_size,
                              hipStream_t stream) {
  const float* in = (const float*)d_in[0];
  const float* cb = (const float*)d_in[1];
  float* out = (float*)d_out;

  float* out_q      = out;                       // 8388608
  float* out_loss   = out + 8388608;             // 131072
  float* out_nn     = out + 8519680;             // 524288
  float* out_cb     = out + 9043968;             // 262144
  float* out_counts = out + 9306112;             // 4096  (total 9310208)

  double* ws_ssq = (double*)d_ws;
  float*  cn32   = (float*)((char*)d_ws + 16);

  hipMemsetAsync(d_ws, 0, 16, stream);
  hipMemsetAsync(out_counts, 0, RQ_K * RQ_C * sizeof(float), stream);

  rq_cnorm_kernel<<<(RQ_K * RQ_C) / 256, 256, 0, stream>>>(cb, cn32);
  rq_main_kernel<<<RQ_N / 128, 256, 0, stream>>>(in, cb, cn32,
                                                 out_q, out_nn, out_counts, ws_ssq);
  rq_final_kernel<<<(RQ_K * RQ_C * RQ_D) / 256, 256, 0, stream>>>(ws_ssq, cb,
                                                                  out_loss, out_cb);
}

// Round 8
// 3873.095 us; speedup vs baseline: 1.1262x; 1.1262x over previous
//
#include <hip/hip_runtime.h>

// ResidualQuantizer: K=4 stages, C=1024 centroids, D=64, N=B*T=131072 rows.
// Outputs (flat f32 concat): quantized[N*D], loss[N], nn_idx[K*N] (as float),
// codebooks_out[K*C*D], counts[K*C].
//
// Bit-matches the checker's numpy-f32 reference pipeline:
//  - dot(residual, centroid): single sequential k-ascending f32 FMA chain
//  - ||c||^2: numpy pairwise-8 sum of separately-rounded squares
//  - score = fmaf(-2, dot, cn)
//  - argmin: first strict min, ascending c (tie across halves -> lower half)
//  - residual/STE updates in reference f32 op order
//
// Parallel layout: 1024 blocks x 256 threads. Waves pair up: waves {2p,2p+1}
// own the same 64 rows; half 0 scans c in [0,512), half 1 scans [512,1024).
// LDS combines the per-row argmin. 16 waves/CU.
//
// ROUND-8 FIX: round 7's __launch_bounds__(256,4) let the compiler shrink to
// 64 VGPRs (8-waves/EU tier) which spilled r[64] to scratch (VGPR 88->64,
// VALUBusy 46->23%, dur 2243->4430us). amdgpu_waves_per_eu(4,4) pins the
// occupancy target so the compiler keeps r[] resident within 128 VGPRs.

#define RQ_K 4
#define RQ_C 1024
#define RQ_D 64
#define RQ_N 131072

// ---------------- kernel 0: centroid norms, numpy pairwise-8 order ----------------
__global__ void rq_cnorm_kernel(const float* __restrict__ cb,
                                float* __restrict__ cn32) {
  int c = blockIdx.x * blockDim.x + threadIdx.x;
  if (c >= RQ_K * RQ_C) return;
  const float* p = cb + (size_t)c * RQ_D;
  float rr[8];
#pragma unroll
  for (int j = 0; j < 8; ++j) {
    float sq = p[j] * p[j];
    asm volatile("" : "+v"(sq));  // forbid fma contraction: square rounds alone
    rr[j] = sq;
  }
#pragma unroll
  for (int i = 8; i < RQ_D; i += 8) {
#pragma unroll
    for (int j = 0; j < 8; ++j) {
      float sq = p[i + j] * p[i + j];
      asm volatile("" : "+v"(sq));
      rr[j] = rr[j] + sq;
    }
  }
  float s = ((rr[0] + rr[1]) + (rr[2] + rr[3])) + ((rr[4] + rr[5]) + (rr[6] + rr[7]));
  cn32[c] = s;
}

// ---------------- kernel 1: main RQ ----------------
__attribute__((amdgpu_waves_per_eu(4, 4)))
__launch_bounds__(256)
__global__ void rq_main_kernel(const float* __restrict__ in,
                               const float* __restrict__ cb,
                               const float* __restrict__ cn32,
                               float* __restrict__ out_q,
                               float* __restrict__ out_nn,
                               float* __restrict__ out_counts,
                               double* __restrict__ ssq_acc) {
  const int wave = threadIdx.x >> 6;
  const int lane = threadIdx.x & 63;
  const int pair = wave >> 1;   // 0,1: which 64-row group in this block
  const int half = wave & 1;    // 0,1: which half of the centroid range
  const int row  = blockIdx.x * 128 + pair * 64 + lane;

  __shared__ float lmv[2][2][64];
  __shared__ int   lmi[2][2][64];
  __shared__ double smem[4];

  float r[RQ_D];  // current residual (f32, reference rounding) — MUST stay in VGPRs
  {
    const float4* ip = reinterpret_cast<const float4*>(in + (size_t)row * RQ_D);
#pragma unroll
    for (int i = 0; i < RQ_D / 4; ++i) {
      float4 v = ip[i];
      r[4 * i + 0] = v.x; r[4 * i + 1] = v.y;
      r[4 * i + 2] = v.z; r[4 * i + 3] = v.w;
    }
  }
  double ssq = 0.0;  // loss partial (counted from half==0 only)

#pragma unroll 1
  for (int k = 0; k < RQ_K; ++k) {
    const float* cbk = cb + (size_t)k * RQ_C * RQ_D;
    const float* cnk = cn32 + k * RQ_C;
    const int c0 = half * (RQ_C / 2);
    float m1 = 3.402823466e38f;
    int i1 = c0;

    // f32 screening over this wave's 512 centroids, 4 per iteration
    // (4 independent chains; each chain is the sequential k-ascending FMA
    // order of the reference). One base pointer + compile-time offsets
    // (0/256/512/768 B) keeps address arithmetic to a single increment.
#pragma unroll 1
    for (int c = c0; c < c0 + RQ_C / 2; c += 4) {
      const float* bp = cbk + (size_t)c * RQ_D;
      float a0 = 0.f, a1 = 0.f, a2 = 0.f, a3 = 0.f;
#pragma unroll
      for (int i = 0; i < RQ_D / 4; ++i) {
        float4 v0 = *reinterpret_cast<const float4*>(bp + 4 * i);
        a0 = fmaf(v0.x, r[4 * i + 0], a0);
        a0 = fmaf(v0.y, r[4 * i + 1], a0);
        a0 = fmaf(v0.z, r[4 * i + 2], a0);
        a0 = fmaf(v0.w, r[4 * i + 3], a0);
        float4 v1 = *reinterpret_cast<const float4*>(bp + RQ_D + 4 * i);
        a1 = fmaf(v1.x, r[4 * i + 0], a1);
        a1 = fmaf(v1.y, r[4 * i + 1], a1);
        a1 = fmaf(v1.z, r[4 * i + 2], a1);
        a1 = fmaf(v1.w, r[4 * i + 3], a1);
        float4 v2 = *reinterpret_cast<const float4*>(bp + 2 * RQ_D + 4 * i);
        a2 = fmaf(v2.x, r[4 * i + 0], a2);
        a2 = fmaf(v2.y, r[4 * i + 1], a2);
        a2 = fmaf(v2.z, r[4 * i + 2], a2);
        a2 = fmaf(v2.w, r[4 * i + 3], a2);
        float4 v3 = *reinterpret_cast<const float4*>(bp + 3 * RQ_D + 4 * i);
        a3 = fmaf(v3.x, r[4 * i + 0], a3);
        a3 = fmaf(v3.y, r[4 * i + 1], a3);
        a3 = fmaf(v3.z, r[4 * i + 2], a3);
        a3 = fmaf(v3.w, r[4 * i + 3], a3);
      }
      float s0 = fmaf(-2.f, a0, cnk[c + 0]);
      float s1 = fmaf(-2.f, a1, cnk[c + 1]);
      float s2 = fmaf(-2.f, a2, cnk[c + 2]);
      float s3 = fmaf(-2.f, a3, cnk[c + 3]);
      bool l0 = s0 < m1; m1 = l0 ? s0 : m1; i1 = l0 ? (c + 0) : i1;
      bool l1 = s1 < m1; m1 = l1 ? s1 : m1; i1 = l1 ? (c + 1) : i1;
      bool l2 = s2 < m1; m1 = l2 ? s2 : m1; i1 = l2 ? (c + 2) : i1;
      bool l3 = s3 < m1; m1 = l3 ? s3 : m1; i1 = l3 ? (c + 3) : i1;
    }

    // cross-wave argmin combine; tie -> half 0 (lower index = first occurrence)
    lmv[pair][half][lane] = m1;
    lmi[pair][half][lane] = i1;
    __syncthreads();
    float ma = lmv[pair][0][lane]; int ia = lmi[pair][0][lane];
    float mb = lmv[pair][1][lane]; int ib = lmi[pair][1][lane];
    const int best = (mb < ma) ? ib : ia;
    __syncthreads();  // LDS reusable next stage

    if (half == 0) {
      out_nn[k * RQ_N + row] = (float)best;
      atomicAdd(&out_counts[k * RQ_C + best], 1.0f);
    }

    // residual / STE update, reference f32 op order (both halves duplicate
    // this deterministically so each keeps a current residual)
    const float4* qp = reinterpret_cast<const float4*>(cbk + (size_t)best * RQ_D);
#pragma unroll
    for (int i = 0; i < RQ_D / 4; ++i) {
      float4 qv = qp[i];
      float qa[4] = {qv.x, qv.y, qv.z, qv.w};
#pragma unroll
      for (int j = 0; j < 4; ++j) {
        int d = 4 * i + j;
        float t = qa[j] - r[d];   // quant - residual
        float qste = r[d] + t;    // straight-through value
        r[d] = r[d] - qste;       // new residual
        ssq = fma((double)t, (double)t, ssq);
      }
    }
  }

  // quantized = sum of quant_ste over stages = in_row - r_final (telescoping;
  // differs from np's pairwise 4-term sum by ~1 ulp, far inside threshold)
  if (half == 0) {
    const float4* ip = reinterpret_cast<const float4*>(in + (size_t)row * RQ_D);
    float4* op = reinterpret_cast<float4*>(out_q + (size_t)row * RQ_D);
#pragma unroll
    for (int i = 0; i < RQ_D / 4; ++i) {
      float4 v = ip[i];
      op[i] = make_float4(v.x - r[4 * i + 0], v.y - r[4 * i + 1],
                          v.z - r[4 * i + 2], v.w - r[4 * i + 3]);
    }
  }

  // block-reduce loss partial (double), half==0 waves only, one atomic/block
#pragma unroll
  for (int off = 32; off > 0; off >>= 1) ssq += __shfl_down(ssq, off);
  if (lane == 0) smem[wave] = (half == 0) ? ssq : 0.0;
  __syncthreads();
  if (threadIdx.x == 0) {
    double t = (smem[0] + smem[1]) + (smem[2] + smem[3]);
    atomicAdd(ssq_acc, t);
  }
}

// ---------------- kernel 2: loss broadcast + codebook copy ----------------
__global__ void rq_final_kernel(const double* __restrict__ ssq_acc,
                                const float* __restrict__ cb,
                                float* __restrict__ out_loss,
                                float* __restrict__ out_cb) {
  int i = blockIdx.x * blockDim.x + threadIdx.x;
  float lossf = (float)(ssq_acc[0] / (double)((long long)RQ_N * RQ_D));
  if (i < RQ_N) out_loss[i] = lossf;
  if (i < RQ_K * RQ_C * RQ_D) out_cb[i] = cb[i];
}

extern "C" void kernel_launch(void* const* d_in, const int* in_sizes, int n_in,
                              void* d_out, int out_size, void* d_ws, size_t ws_size,
                              hipStream_t stream) {
  const float* in = (const float*)d_in[0];
  const float* cb = (const float*)d_in[1];
  float* out = (float*)d_out;

  float* out_q      = out;                       // 8388608
  float* out_loss   = out + 8388608;             // 131072
  float* out_nn     = out + 8519680;             // 524288
  float* out_cb     = out + 9043968;             // 262144
  float* out_counts = out + 9306112;             // 4096  (total 9310208)

  double* ws_ssq = (double*)d_ws;
  float*  cn32   = (float*)((char*)d_ws + 16);

  hipMemsetAsync(d_ws, 0, 16, stream);
  hipMemsetAsync(out_counts, 0, RQ_K * RQ_C * sizeof(float), stream);

  rq_cnorm_kernel<<<(RQ_K * RQ_C) / 256, 256, 0, stream>>>(cb, cn32);
  rq_main_kernel<<<RQ_N / 128, 256, 0, stream>>>(in, cb, cn32,
                                                 out_q, out_nn, out_counts, ws_ssq);
  rq_final_kernel<<<(RQ_K * RQ_C * RQ_D) / 256, 256, 0, stream>>>(ws_ssq, cb,
                                                                  out_loss, out_cb);
}

// Round 9
// 3774.409 us; speedup vs baseline: 1.1557x; 1.0261x over previous
//
#include <hip/hip_runtime.h>

// ResidualQuantizer: K=4 stages, C=1024 centroids, D=64, N=B*T=131072 rows.
// Outputs (flat f32 concat): quantized[N*D], loss[N], nn_idx[K*N] (as float),
// codebooks_out[K*C*D], counts[K*C].
//
// Bit-matches the checker's numpy-f32 reference pipeline:
//  - dot(residual, centroid): single sequential k-ascending f32 FMA chain
//  - ||c||^2: numpy pairwise-8 sum of separately-rounded squares
//  - score = fmaf(-2, dot, cn)
//  - argmin: first strict min, ascending c (tie across halves -> lower half)
//  - residual/STE updates in reference f32 op order
//
// Parallel layout: 1024 blocks x 256 threads. Waves pair up: waves {2p,2p+1}
// own the same 64 rows; half 0 scans c in [0,512), half 1 scans [512,1024).
// LDS combines the per-row argmin. 16 waves/CU.
//
// REGISTER-BUDGET NOTE (rounds 4/7/8 measured): cap 256 (launch_bounds(256,2))
// -> allocator picks 88 VGPRs, r[64] resident, no spill. cap 128 (minwaves 4
// or waves_per_eu(4,4)) -> allocator overshoots to 64 VGPRs and spills r[]
// to scratch (dur 2x). So we keep minwaves=2 and let the GRID (1024 blocks)
// supply 16 waves/CU; the 88-VGPR footprint allows exactly that residency.

#define RQ_K 4
#define RQ_C 1024
#define RQ_D 64
#define RQ_N 131072

// ---------------- kernel 0: centroid norms, numpy pairwise-8 order ----------------
__global__ void rq_cnorm_kernel(const float* __restrict__ cb,
                                float* __restrict__ cn32) {
  int c = blockIdx.x * blockDim.x + threadIdx.x;
  if (c >= RQ_K * RQ_C) return;
  const float* p = cb + (size_t)c * RQ_D;
  float rr[8];
#pragma unroll
  for (int j = 0; j < 8; ++j) {
    float sq = p[j] * p[j];
    asm volatile("" : "+v"(sq));  // forbid fma contraction: square rounds alone
    rr[j] = sq;
  }
#pragma unroll
  for (int i = 8; i < RQ_D; i += 8) {
#pragma unroll
    for (int j = 0; j < 8; ++j) {
      float sq = p[i + j] * p[i + j];
      asm volatile("" : "+v"(sq));
      rr[j] = rr[j] + sq;
    }
  }
  float s = ((rr[0] + rr[1]) + (rr[2] + rr[3])) + ((rr[4] + rr[5]) + (rr[6] + rr[7]));
  cn32[c] = s;
}

// ---------------- kernel 1: main RQ ----------------
__launch_bounds__(256, 2)
__global__ void rq_main_kernel(const float* __restrict__ in,
                               const float* __restrict__ cb,
                               const float* __restrict__ cn32,
                               float* __restrict__ out_q,
                               float* __restrict__ out_nn,
                               float* __restrict__ out_counts,
                               double* __restrict__ ssq_acc) {
  const int wave = threadIdx.x >> 6;
  const int lane = threadIdx.x & 63;
  const int pair = wave >> 1;   // 0,1: which 64-row group in this block
  const int half = wave & 1;    // 0,1: which half of the centroid range
  const int row  = blockIdx.x * 128 + pair * 64 + lane;

  __shared__ float lmv[2][2][64];
  __shared__ int   lmi[2][2][64];
  __shared__ double smem[4];

  float r[RQ_D];  // current residual (f32, reference rounding) — stays in VGPRs
  {
    const float4* ip = reinterpret_cast<const float4*>(in + (size_t)row * RQ_D);
#pragma unroll
    for (int i = 0; i < RQ_D / 4; ++i) {
      float4 v = ip[i];
      r[4 * i + 0] = v.x; r[4 * i + 1] = v.y;
      r[4 * i + 2] = v.z; r[4 * i + 3] = v.w;
    }
  }
  double ssq = 0.0;  // loss partial (counted from half==0 only)

#pragma unroll 1
  for (int k = 0; k < RQ_K; ++k) {
    const float* cbk = cb + (size_t)k * RQ_C * RQ_D;
    const float* cnk = cn32 + k * RQ_C;
    const int c0 = half * (RQ_C / 2);
    float m1 = 3.402823466e38f;
    int i1 = c0;

    // f32 screening over this wave's 512 centroids, 4 per iteration
    // (4 independent chains; each chain is the sequential k-ascending FMA
    // order of the reference). One base pointer + compile-time offsets.
#pragma unroll 1
    for (int c = c0; c < c0 + RQ_C / 2; c += 4) {
      const float* bp = cbk + (size_t)c * RQ_D;
      float a0 = 0.f, a1 = 0.f, a2 = 0.f, a3 = 0.f;
#pragma unroll
      for (int i = 0; i < RQ_D / 4; ++i) {
        float4 v0 = *reinterpret_cast<const float4*>(bp + 4 * i);
        a0 = fmaf(v0.x, r[4 * i + 0], a0);
        a0 = fmaf(v0.y, r[4 * i + 1], a0);
        a0 = fmaf(v0.z, r[4 * i + 2], a0);
        a0 = fmaf(v0.w, r[4 * i + 3], a0);
        float4 v1 = *reinterpret_cast<const float4*>(bp + RQ_D + 4 * i);
        a1 = fmaf(v1.x, r[4 * i + 0], a1);
        a1 = fmaf(v1.y, r[4 * i + 1], a1);
        a1 = fmaf(v1.z, r[4 * i + 2], a1);
        a1 = fmaf(v1.w, r[4 * i + 3], a1);
        float4 v2 = *reinterpret_cast<const float4*>(bp + 2 * RQ_D + 4 * i);
        a2 = fmaf(v2.x, r[4 * i + 0], a2);
        a2 = fmaf(v2.y, r[4 * i + 1], a2);
        a2 = fmaf(v2.z, r[4 * i + 2], a2);
        a2 = fmaf(v2.w, r[4 * i + 3], a2);
        float4 v3 = *reinterpret_cast<const float4*>(bp + 3 * RQ_D + 4 * i);
        a3 = fmaf(v3.x, r[4 * i + 0], a3);
        a3 = fmaf(v3.y, r[4 * i + 1], a3);
        a3 = fmaf(v3.z, r[4 * i + 2], a3);
        a3 = fmaf(v3.w, r[4 * i + 3], a3);
      }
      float s0 = fmaf(-2.f, a0, cnk[c + 0]);
      float s1 = fmaf(-2.f, a1, cnk[c + 1]);
      float s2 = fmaf(-2.f, a2, cnk[c + 2]);
      float s3 = fmaf(-2.f, a3, cnk[c + 3]);
      bool l0 = s0 < m1; m1 = l0 ? s0 : m1; i1 = l0 ? (c + 0) : i1;
      bool l1 = s1 < m1; m1 = l1 ? s1 : m1; i1 = l1 ? (c + 1) : i1;
      bool l2 = s2 < m1; m1 = l2 ? s2 : m1; i1 = l2 ? (c + 2) : i1;
      bool l3 = s3 < m1; m1 = l3 ? s3 : m1; i1 = l3 ? (c + 3) : i1;
    }

    // cross-wave argmin combine; tie -> half 0 (lower index = first occurrence)
    lmv[pair][half][lane] = m1;
    lmi[pair][half][lane] = i1;
    __syncthreads();
    float ma = lmv[pair][0][lane]; int ia = lmi[pair][0][lane];
    float mb = lmv[pair][1][lane]; int ib = lmi[pair][1][lane];
    const int best = (mb < ma) ? ib : ia;
    __syncthreads();  // LDS reusable next stage

    if (half == 0) {
      out_nn[k * RQ_N + row] = (float)best;
      atomicAdd(&out_counts[k * RQ_C + best], 1.0f);
    }

    // residual / STE update, reference f32 op order (both halves duplicate
    // this deterministically so each keeps a current residual)
    const float4* qp = reinterpret_cast<const float4*>(cbk + (size_t)best * RQ_D);
#pragma unroll
    for (int i = 0; i < RQ_D / 4; ++i) {
      float4 qv = qp[i];
      float qa[4] = {qv.x, qv.y, qv.z, qv.w};
#pragma unroll
      for (int j = 0; j < 4; ++j) {
        int d = 4 * i + j;
        float t = qa[j] - r[d];   // quant - residual
        float qste = r[d] + t;    // straight-through value
        r[d] = r[d] - qste;       // new residual
        ssq = fma((double)t, (double)t, ssq);
      }
    }
  }

  // quantized = sum of quant_ste over stages = in_row - r_final (telescoping;
  // differs from np's pairwise 4-term sum by ~1 ulp, far inside threshold)
  if (half == 0) {
    const float4* ip = reinterpret_cast<const float4*>(in + (size_t)row * RQ_D);
    float4* op = reinterpret_cast<float4*>(out_q + (size_t)row * RQ_D);
#pragma unroll
    for (int i = 0; i < RQ_D / 4; ++i) {
      float4 v = ip[i];
      op[i] = make_float4(v.x - r[4 * i + 0], v.y - r[4 * i + 1],
                          v.z - r[4 * i + 2], v.w - r[4 * i + 3]);
    }
  }

  // block-reduce loss partial (double), half==0 waves only, one atomic/block
#pragma unroll
  for (int off = 32; off > 0; off >>= 1) ssq += __shfl_down(ssq, off);
  if (lane == 0) smem[wave] = (half == 0) ? ssq : 0.0;
  __syncthreads();
  if (threadIdx.x == 0) {
    double t = (smem[0] + smem[1]) + (smem[2] + smem[3]);
    atomicAdd(ssq_acc, t);
  }
}

// ---------------- kernel 2: loss broadcast + codebook copy ----------------
__global__ void rq_final_kernel(const double* __restrict__ ssq_acc,
                                const float* __restrict__ cb,
                                float* __restrict__ out_loss,
                                float* __restrict__ out_cb) {
  int i = blockIdx.x * blockDim.x + threadIdx.x;
  float lossf = (float)(ssq_acc[0] / (double)((long long)RQ_N * RQ_D));
  if (i < RQ_N) out_loss[i] = lossf;
  if (i < RQ_K * RQ_C * RQ_D) out_cb[i] = cb[i];
}

extern "C" void kernel_launch(void* const* d_in, const int* in_sizes, int n_in,
                              void* d_out, int out_size, void* d_ws, size_t ws_size,
                              hipStream_t stream) {
  const float* in = (const float*)d_in[0];
  const float* cb = (const float*)d_in[1];
  float* out = (float*)d_out;

  float* out_q      = out;                       // 8388608
  float* out_loss   = out + 8388608;             // 131072
  float* out_nn     = out + 8519680;             // 524288
  float* out_cb     = out + 9043968;             // 262144
  float* out_counts = out + 9306112;             // 4096  (total 9310208)

  double* ws_ssq = (double*)d_ws;
  float*  cn32   = (float*)((char*)d_ws + 16);

  hipMemsetAsync(d_ws, 0, 16, stream);
  hipMemsetAsync(out_counts, 0, RQ_K * RQ_C * sizeof(float), stream);

  rq_cnorm_kernel<<<(RQ_K * RQ_C) / 256, 256, 0, stream>>>(cb, cn32);
  rq_main_kernel<<<RQ_N / 128, 256, 0, stream>>>(in, cb, cn32,
                                                 out_q, out_nn, out_counts, ws_ssq);
  rq_final_kernel<<<(RQ_K * RQ_C * RQ_D) / 256, 256, 0, stream>>>(ws_ssq, cb,
                                                                  out_loss, out_cb);
}

// Round 10
// 1522.216 us; speedup vs baseline: 2.8656x; 2.4795x over previous
//
#include <hip/hip_runtime.h>

// ResidualQuantizer: K=4 stages, C=1024 centroids, D=64, N=B*T=131072 rows.
// Outputs (flat f32 concat): quantized[N*D], loss[N], nn_idx[K*N] (as float),
// codebooks_out[K*C*D], counts[K*C].
//
// Bit-matches the checker's numpy-f32 reference pipeline:
//  - dot(residual, centroid): single sequential k-ascending f32 FMA chain
//  - ||c||^2: numpy pairwise-8 sum of separately-rounded squares
//  - score = fmaf(-2, dot, cn)
//  - argmin: first strict min, ascending c (tie across halves -> lower half)
//  - residual/STE updates in reference f32 op order
//
// Parallel layout: 1024 blocks x 256 threads. Waves pair up: waves {2p,2p+1}
// own the same 64 rows; half 0 scans c in [0,512), half 1 scans [512,1024).
// LDS combines the per-row argmin. 16 waves/CU.
//
// UNIFORMITY NOTE (rounds 4 vs 7-9, measured): when the centroid index is
// provably wave-uniform, the compiler emits s_load for codebook/cn and SGPR
// holds the centroid data (round 4: SGPR=112, VGPR=88, no spill, 2243us).
// Deriving c0 from threadIdx.x defeated uniformity analysis (SGPR=32), all
// codebook loads became per-lane vector loads, r[64] spilled (VGPR=64,
// WRITE_SIZE +12MB, dur 3774-4430us). readfirstlane restores the SGPR path.

#define RQ_K 4
#define RQ_C 1024
#define RQ_D 64
#define RQ_N 131072

// ---------------- kernel 0: centroid norms, numpy pairwise-8 order ----------------
__global__ void rq_cnorm_kernel(const float* __restrict__ cb,
                                float* __restrict__ cn32) {
  int c = blockIdx.x * blockDim.x + threadIdx.x;
  if (c >= RQ_K * RQ_C) return;
  const float* p = cb + (size_t)c * RQ_D;
  float rr[8];
#pragma unroll
  for (int j = 0; j < 8; ++j) {
    float sq = p[j] * p[j];
    asm volatile("" : "+v"(sq));  // forbid fma contraction: square rounds alone
    rr[j] = sq;
  }
#pragma unroll
  for (int i = 8; i < RQ_D; i += 8) {
#pragma unroll
    for (int j = 0; j < 8; ++j) {
      float sq = p[i + j] * p[i + j];
      asm volatile("" : "+v"(sq));
      rr[j] = rr[j] + sq;
    }
  }
  float s = ((rr[0] + rr[1]) + (rr[2] + rr[3])) + ((rr[4] + rr[5]) + (rr[6] + rr[7]));
  cn32[c] = s;
}

// ---------------- kernel 1: main RQ ----------------
__launch_bounds__(256, 2)
__global__ void rq_main_kernel(const float* __restrict__ in,
                               const float* __restrict__ cb,
                               const float* __restrict__ cn32,
                               float* __restrict__ out_q,
                               float* __restrict__ out_nn,
                               float* __restrict__ out_counts,
                               double* __restrict__ ssq_acc) {
  // readfirstlane: tid>>6 is uniform within a wave by construction; moving it
  // to an SGPR makes the uniformity provable so codebook loads stay scalar.
  const int wave = __builtin_amdgcn_readfirstlane(threadIdx.x >> 6);
  const int lane = threadIdx.x & 63;
  const int pair = wave >> 1;   // 0,1: which 64-row group in this block (SGPR)
  const int half = wave & 1;    // 0,1: which half of the centroid range (SGPR)
  const int row  = blockIdx.x * 128 + pair * 64 + lane;

  __shared__ float lmv[2][2][64];
  __shared__ int   lmi[2][2][64];
  __shared__ double smem[4];

  float r[RQ_D];  // current residual (f32, reference rounding) — stays in VGPRs
  {
    const float4* ip = reinterpret_cast<const float4*>(in + (size_t)row * RQ_D);
#pragma unroll
    for (int i = 0; i < RQ_D / 4; ++i) {
      float4 v = ip[i];
      r[4 * i + 0] = v.x; r[4 * i + 1] = v.y;
      r[4 * i + 2] = v.z; r[4 * i + 3] = v.w;
    }
  }
  double ssq = 0.0;  // loss partial (counted from half==0 only)

#pragma unroll 1
  for (int k = 0; k < RQ_K; ++k) {
    const float* cbk = cb + (size_t)k * RQ_C * RQ_D;
    const float* cnk = cn32 + k * RQ_C;
    const int c0 = __builtin_amdgcn_readfirstlane(half * (RQ_C / 2));
    float m1 = 3.402823466e38f;
    int i1 = c0;

    // f32 screening over this wave's 512 centroids, 4 per iteration
    // (4 independent chains; each chain is the sequential k-ascending FMA
    // order of the reference). c is uniform -> codebook/cn via scalar loads.
#pragma unroll 1
    for (int c = c0; c < c0 + RQ_C / 2; c += 4) {
      const float* bp = cbk + (size_t)c * RQ_D;
      float a0 = 0.f, a1 = 0.f, a2 = 0.f, a3 = 0.f;
#pragma unroll
      for (int i = 0; i < RQ_D / 4; ++i) {
        float4 v0 = *reinterpret_cast<const float4*>(bp + 4 * i);
        a0 = fmaf(v0.x, r[4 * i + 0], a0);
        a0 = fmaf(v0.y, r[4 * i + 1], a0);
        a0 = fmaf(v0.z, r[4 * i + 2], a0);
        a0 = fmaf(v0.w, r[4 * i + 3], a0);
        float4 v1 = *reinterpret_cast<const float4*>(bp + RQ_D + 4 * i);
        a1 = fmaf(v1.x, r[4 * i + 0], a1);
        a1 = fmaf(v1.y, r[4 * i + 1], a1);
        a1 = fmaf(v1.z, r[4 * i + 2], a1);
        a1 = fmaf(v1.w, r[4 * i + 3], a1);
        float4 v2 = *reinterpret_cast<const float4*>(bp + 2 * RQ_D + 4 * i);
        a2 = fmaf(v2.x, r[4 * i + 0], a2);
        a2 = fmaf(v2.y, r[4 * i + 1], a2);
        a2 = fmaf(v2.z, r[4 * i + 2], a2);
        a2 = fmaf(v2.w, r[4 * i + 3], a2);
        float4 v3 = *reinterpret_cast<const float4*>(bp + 3 * RQ_D + 4 * i);
        a3 = fmaf(v3.x, r[4 * i + 0], a3);
        a3 = fmaf(v3.y, r[4 * i + 1], a3);
        a3 = fmaf(v3.z, r[4 * i + 2], a3);
        a3 = fmaf(v3.w, r[4 * i + 3], a3);
      }
      float s0 = fmaf(-2.f, a0, cnk[c + 0]);
      float s1 = fmaf(-2.f, a1, cnk[c + 1]);
      float s2 = fmaf(-2.f, a2, cnk[c + 2]);
      float s3 = fmaf(-2.f, a3, cnk[c + 3]);
      bool l0 = s0 < m1; m1 = l0 ? s0 : m1; i1 = l0 ? (c + 0) : i1;
      bool l1 = s1 < m1; m1 = l1 ? s1 : m1; i1 = l1 ? (c + 1) : i1;
      bool l2 = s2 < m1; m1 = l2 ? s2 : m1; i1 = l2 ? (c + 2) : i1;
      bool l3 = s3 < m1; m1 = l3 ? s3 : m1; i1 = l3 ? (c + 3) : i1;
    }

    // cross-wave argmin combine; tie -> half 0 (lower index = first occurrence)
    lmv[pair][half][lane] = m1;
    lmi[pair][half][lane] = i1;
    __syncthreads();
    float ma = lmv[pair][0][lane]; int ia = lmi[pair][0][lane];
    float mb = lmv[pair][1][lane]; int ib = lmi[pair][1][lane];
    const int best = (mb < ma) ? ib : ia;
    __syncthreads();  // LDS reusable next stage

    if (half == 0) {
      out_nn[k * RQ_N + row] = (float)best;
      atomicAdd(&out_counts[k * RQ_C + best], 1.0f);
    }

    // residual / STE update, reference f32 op order (both halves duplicate
    // this deterministically so each keeps a current residual). best is
    // divergent (per-row) -> these stay vector loads, as they must.
    const float4* qp = reinterpret_cast<const float4*>(cbk + (size_t)best * RQ_D);
#pragma unroll
    for (int i = 0; i < RQ_D / 4; ++i) {
      float4 qv = qp[i];
      float qa[4] = {qv.x, qv.y, qv.z, qv.w};
#pragma unroll
      for (int j = 0; j < 4; ++j) {
        int d = 4 * i + j;
        float t = qa[j] - r[d];   // quant - residual
        float qste = r[d] + t;    // straight-through value
        r[d] = r[d] - qste;       // new residual
        ssq = fma((double)t, (double)t, ssq);
      }
    }
  }

  // quantized = sum of quant_ste over stages = in_row - r_final (telescoping;
  // differs from np's pairwise 4-term sum by ~1 ulp, far inside threshold)
  if (half == 0) {
    const float4* ip = reinterpret_cast<const float4*>(in + (size_t)row * RQ_D);
    float4* op = reinterpret_cast<float4*>(out_q + (size_t)row * RQ_D);
#pragma unroll
    for (int i = 0; i < RQ_D / 4; ++i) {
      float4 v = ip[i];
      op[i] = make_float4(v.x - r[4 * i + 0], v.y - r[4 * i + 1],
                          v.z - r[4 * i + 2], v.w - r[4 * i + 3]);
    }
  }

  // block-reduce loss partial (double), half==0 waves only, one atomic/block
#pragma unroll
  for (int off = 32; off > 0; off >>= 1) ssq += __shfl_down(ssq, off);
  if (lane == 0) smem[wave] = (half == 0) ? ssq : 0.0;
  __syncthreads();
  if (threadIdx.x == 0) {
    double t = (smem[0] + smem[1]) + (smem[2] + smem[3]);
    atomicAdd(ssq_acc, t);
  }
}

// ---------------- kernel 2: loss broadcast + codebook copy ----------------
__global__ void rq_final_kernel(const double* __restrict__ ssq_acc,
                                const float* __restrict__ cb,
                                float* __restrict__ out_loss,
                                float* __restrict__ out_cb) {
  int i = blockIdx.x * blockDim.x + threadIdx.x;
  float lossf = (float)(ssq_acc[0] / (double)((long long)RQ_N * RQ_D));
  if (i < RQ_N) out_loss[i] = lossf;
  if (i < RQ_K * RQ_C * RQ_D) out_cb[i] = cb[i];
}

extern "C" void kernel_launch(void* const* d_in, const int* in_sizes, int n_in,
                              void* d_out, int out_size, void* d_ws, size_t ws_size,
                              hipStream_t stream) {
  const float* in = (const float*)d_in[0];
  const float* cb = (const float*)d_in[1];
  float* out = (float*)d_out;

  float* out_q      = out;                       // 8388608
  float* out_loss   = out + 8388608;             // 131072
  float* out_nn     = out + 8519680;             // 524288
  float* out_cb     = out + 9043968;             // 262144
  float* out_counts = out + 9306112;             // 4096  (total 9310208)

  double* ws_ssq = (double*)d_ws;
  float*  cn32   = (float*)((char*)d_ws + 16);

  hipMemsetAsync(d_ws, 0, 16, stream);
  hipMemsetAsync(out_counts, 0, RQ_K * RQ_C * sizeof(float), stream);

  rq_cnorm_kernel<<<(RQ_K * RQ_C) / 256, 256, 0, stream>>>(cb, cn32);
  rq_main_kernel<<<RQ_N / 128, 256, 0, stream>>>(in, cb, cn32,
                                                 out_q, out_nn, out_counts, ws_ssq);
  rq_final_kernel<<<(RQ_K * RQ_C * RQ_D) / 256, 256, 0, stream>>>(ws_ssq, cb,
                                                                  out_loss, out_cb);
}

// Round 13
// 1419.992 us; speedup vs baseline: 3.0718x; 1.0720x over previous
//
#include <hip/hip_runtime.h>

// ResidualQuantizer: K=4 stages, C=1024 centroids, D=64, N=B*T=131072 rows.
// Outputs (flat f32 concat): quantized[N*D], loss[N], nn_idx[K*N] (as float),
// codebooks_out[K*C*D], counts[K*C].
//
// Bit-matches the checker's numpy-f32 reference pipeline:
//  - dot(residual, centroid): single sequential k-ascending f32 FMA chain
//  - ||c||^2: numpy pairwise-8 sum of separately-rounded squares
//  - score = fmaf(-2, dot, cn)
//  - argmin: first strict min, ascending c (tie across halves -> lower half)
//  - residual/STE updates in reference f32 op order
//
// Parallel layout: 1024 blocks x 256 threads. Waves pair up: waves {2p,2p+1}
// own the same 64 rows; half 0 scans c in [0,512), half 1 scans [512,1024).
// LDS combines the per-row argmin. 16 waves/CU.
//
// UNIFORMITY (r4 vs r7-10, measured): centroid index must be PROVABLY
// wave-uniform (readfirstlane) so codebook/cn use s_load into SGPRs
// (SGPR=112). Divergent c0 -> vector loads, SGPR=32, 2.5x slower.
//
// REGISTER BUDGET (r10 post-mortem): every round so far spilled r[64]
// (VGPR_Count=64, WRITE_SIZE ~11.5MB over real outputs; VALU ~7x inflated
// by spill reloads). True live set in the uniform regime is ~94 regs.
// amdgpu_waves_per_eu(4,4) pins the allocator to the 128-reg/4-wave tier:
// removes the 8-wave-tier incentive to shrink to 64, and 4 waves/EU is
// exactly what the 1024-block grid supplies anyway.

#define RQ_K 4
#define RQ_C 1024
#define RQ_D 64
#define RQ_N 131072

// ---------------- kernel 0: centroid norms, numpy pairwise-8 order ----------------
__global__ void rq_cnorm_kernel(const float* __restrict__ cb,
                                float* __restrict__ cn32) {
  int c = blockIdx.x * blockDim.x + threadIdx.x;
  if (c >= RQ_K * RQ_C) return;
  const float* p = cb + (size_t)c * RQ_D;
  float rr[8];
#pragma unroll
  for (int j = 0; j < 8; ++j) {
    float sq = p[j] * p[j];
    asm volatile("" : "+v"(sq));  // forbid fma contraction: square rounds alone
    rr[j] = sq;
  }
#pragma unroll
  for (int i = 8; i < RQ_D; i += 8) {
#pragma unroll
    for (int j = 0; j < 8; ++j) {
      float sq = p[i + j] * p[i + j];
      asm volatile("" : "+v"(sq));
      rr[j] = rr[j] + sq;
    }
  }
  float s = ((rr[0] + rr[1]) + (rr[2] + rr[3])) + ((rr[4] + rr[5]) + (rr[6] + rr[7]));
  cn32[c] = s;
}

// ---------------- kernel 1: main RQ ----------------
__attribute__((amdgpu_waves_per_eu(4, 4)))
__launch_bounds__(256)
__global__ void rq_main_kernel(const float* __restrict__ in,
                               const float* __restrict__ cb,
                               const float* __restrict__ cn32,
                               float* __restrict__ out_q,
                               float* __restrict__ out_nn,
                               float* __restrict__ out_counts,
                               double* __restrict__ ssq_acc) {
  // readfirstlane: tid>>6 is uniform within a wave by construction; moving it
  // to an SGPR makes the uniformity provable so codebook loads stay scalar.
  const int wave = __builtin_amdgcn_readfirstlane(threadIdx.x >> 6);
  const int lane = threadIdx.x & 63;
  const int pair = wave >> 1;   // 0,1: which 64-row group in this block (SGPR)
  const int half = wave & 1;    // 0,1: which half of the centroid range (SGPR)
  const int row  = blockIdx.x * 128 + pair * 64 + lane;

  __shared__ float lmv[2][2][64];
  __shared__ int   lmi[2][2][64];
  __shared__ double smem[4];

  float r[RQ_D];  // current residual (f32, reference rounding) — target: VGPRs
  {
    const float4* ip = reinterpret_cast<const float4*>(in + (size_t)row * RQ_D);
#pragma unroll
    for (int i = 0; i < RQ_D / 4; ++i) {
      float4 v = ip[i];
      r[4 * i + 0] = v.x; r[4 * i + 1] = v.y;
      r[4 * i + 2] = v.z; r[4 * i + 3] = v.w;
    }
  }
  double ssq = 0.0;  // loss partial (counted from half==0 only)

#pragma unroll 1
  for (int k = 0; k < RQ_K; ++k) {
    const float* cbk = cb + (size_t)k * RQ_C * RQ_D;
    const float* cnk = cn32 + k * RQ_C;
    const int c0 = __builtin_amdgcn_readfirstlane(half * (RQ_C / 2));
    float m1 = 3.402823466e38f;
    int i1 = c0;

    // f32 screening over this wave's 512 centroids, 4 per iteration
    // (4 independent chains; each chain is the sequential k-ascending FMA
    // order of the reference). c is uniform -> codebook/cn via scalar loads.
#pragma unroll 1
    for (int c = c0; c < c0 + RQ_C / 2; c += 4) {
      const float* bp = cbk + (size_t)c * RQ_D;
      float a0 = 0.f, a1 = 0.f, a2 = 0.f, a3 = 0.f;
#pragma unroll
      for (int i = 0; i < RQ_D / 4; ++i) {
        float4 v0 = *reinterpret_cast<const float4*>(bp + 4 * i);
        a0 = fmaf(v0.x, r[4 * i + 0], a0);
        a0 = fmaf(v0.y, r[4 * i + 1], a0);
        a0 = fmaf(v0.z, r[4 * i + 2], a0);
        a0 = fmaf(v0.w, r[4 * i + 3], a0);
        float4 v1 = *reinterpret_cast<const float4*>(bp + RQ_D + 4 * i);
        a1 = fmaf(v1.x, r[4 * i + 0], a1);
        a1 = fmaf(v1.y, r[4 * i + 1], a1);
        a1 = fmaf(v1.z, r[4 * i + 2], a1);
        a1 = fmaf(v1.w, r[4 * i + 3], a1);
        float4 v2 = *reinterpret_cast<const float4*>(bp + 2 * RQ_D + 4 * i);
        a2 = fmaf(v2.x, r[4 * i + 0], a2);
        a2 = fmaf(v2.y, r[4 * i + 1], a2);
        a2 = fmaf(v2.z, r[4 * i + 2], a2);
        a2 = fmaf(v2.w, r[4 * i + 3], a2);
        float4 v3 = *reinterpret_cast<const float4*>(bp + 3 * RQ_D + 4 * i);
        a3 = fmaf(v3.x, r[4 * i + 0], a3);
        a3 = fmaf(v3.y, r[4 * i + 1], a3);
        a3 = fmaf(v3.z, r[4 * i + 2], a3);
        a3 = fmaf(v3.w, r[4 * i + 3], a3);
      }
      float s0 = fmaf(-2.f, a0, cnk[c + 0]);
      float s1 = fmaf(-2.f, a1, cnk[c + 1]);
      float s2 = fmaf(-2.f, a2, cnk[c + 2]);
      float s3 = fmaf(-2.f, a3, cnk[c + 3]);
      bool l0 = s0 < m1; m1 = l0 ? s0 : m1; i1 = l0 ? (c + 0) : i1;
      bool l1 = s1 < m1; m1 = l1 ? s1 : m1; i1 = l1 ? (c + 1) : i1;
      bool l2 = s2 < m1; m1 = l2 ? s2 : m1; i1 = l2 ? (c + 2) : i1;
      bool l3 = s3 < m1; m1 = l3 ? s3 : m1; i1 = l3 ? (c + 3) : i1;
    }

    // cross-wave argmin combine; tie -> half 0 (lower index = first occurrence)
    lmv[pair][half][lane] = m1;
    lmi[pair][half][lane] = i1;
    __syncthreads();
    float ma = lmv[pair][0][lane]; int ia = lmi[pair][0][lane];
    float mb = lmv[pair][1][lane]; int ib = lmi[pair][1][lane];
    const int best = (mb < ma) ? ib : ia;
    __syncthreads();  // LDS reusable next stage

    if (half == 0) {
      out_nn[k * RQ_N + row] = (float)best;
      atomicAdd(&out_counts[k * RQ_C + best], 1.0f);
    }

    // residual / STE update, reference f32 op order (both halves duplicate
    // this deterministically so each keeps a current residual). best is
    // divergent (per-row) -> these stay vector loads, as they must.
    const float4* qp = reinterpret_cast<const float4*>(cbk + (size_t)best * RQ_D);
#pragma unroll
    for (int i = 0; i < RQ_D / 4; ++i) {
      float4 qv = qp[i];
      float qa[4] = {qv.x, qv.y, qv.z, qv.w};
#pragma unroll
      for (int j = 0; j < 4; ++j) {
        int d = 4 * i + j;
        float t = qa[j] - r[d];   // quant - residual
        float qste = r[d] + t;    // straight-through value
        r[d] = r[d] - qste;       // new residual
        ssq = fma((double)t, (double)t, ssq);
      }
    }
  }

  // quantized = sum of quant_ste over stages = in_row - r_final (telescoping;
  // differs from np's pairwise 4-term sum by ~1 ulp, far inside threshold)
  if (half == 0) {
    const float4* ip = reinterpret_cast<const float4*>(in + (size_t)row * RQ_D);
    float4* op = reinterpret_cast<float4*>(out_q + (size_t)row * RQ_D);
#pragma unroll
    for (int i = 0; i < RQ_D / 4; ++i) {
      float4 v = ip[i];
      op[i] = make_float4(v.x - r[4 * i + 0], v.y - r[4 * i + 1],
                          v.z - r[4 * i + 2], v.w - r[4 * i + 3]);
    }
  }

  // block-reduce loss partial (double), half==0 waves only, one atomic/block
#pragma unroll
  for (int off = 32; off > 0; off >>= 1) ssq += __shfl_down(ssq, off);
  if (lane == 0) smem[wave] = (half == 0) ? ssq : 0.0;
  __syncthreads();
  if (threadIdx.x == 0) {
    double t = (smem[0] + smem[1]) + (smem[2] + smem[3]);
    atomicAdd(ssq_acc, t);
  }
}

// ---------------- kernel 2: loss broadcast + codebook copy ----------------
__global__ void rq_final_kernel(const double* __restrict__ ssq_acc,
                                const float* __restrict__ cb,
                                float* __restrict__ out_loss,
                                float* __restrict__ out_cb) {
  int i = blockIdx.x * blockDim.x + threadIdx.x;
  float lossf = (float)(ssq_acc[0] / (double)((long long)RQ_N * RQ_D));
  if (i < RQ_N) out_loss[i] = lossf;
  if (i < RQ_K * RQ_C * RQ_D) out_cb[i] = cb[i];
}

extern "C" void kernel_launch(void* const* d_in, const int* in_sizes, int n_in,
                              void* d_out, int out_size, void* d_ws, size_t ws_size,
                              hipStream_t stream) {
  const float* in = (const float*)d_in[0];
  const float* cb = (const float*)d_in[1];
  float* out = (float*)d_out;

  float* out_q      = out;                       // 8388608
  float* out_loss   = out + 8388608;             // 131072
  float* out_nn     = out + 8519680;             // 524288
  float* out_cb     = out + 9043968;             // 262144
  float* out_counts = out + 9306112;             // 4096  (total 9310208)

  double* ws_ssq = (double*)d_ws;
  float*  cn32   = (float*)((char*)d_ws + 16);

  hipMemsetAsync(d_ws, 0, 16, stream);
  hipMemsetAsync(out_counts, 0, RQ_K * RQ_C * sizeof(float), stream);

  rq_cnorm_kernel<<<(RQ_K * RQ_C) / 256, 256, 0, stream>>>(cb, cn32);
  rq_main_kernel<<<RQ_N / 128, 256, 0, stream>>>(in, cb, cn32,
                                                 out_q, out_nn, out_counts, ws_ssq);
  rq_final_kernel<<<(RQ_K * RQ_C * RQ_D) / 256, 256, 0, stream>>>(ws_ssq, cb,
                                                                  out_loss, out_cb);
}

// Round 14
// 1317.226 us; speedup vs baseline: 3.3115x; 1.0780x over previous
//
#include <hip/hip_runtime.h>

// ResidualQuantizer: K=4 stages, C=1024 centroids, D=64, N=B*T=131072 rows.
// Outputs (flat f32 concat): quantized[N*D], loss[N], nn_idx[K*N] (as float),
// codebooks_out[K*C*D], counts[K*C].
//
// Bit-matches the checker's numpy-f32 reference pipeline:
//  - dot(residual, centroid): sequential d-ascending f32 FMA chain per centroid
//  - ||c||^2: numpy pairwise-8 sum of separately-rounded squares
//  - score = fmaf(-2, dot, cn)
//  - argmin: first strict min, ascending c (ascending-partition tie-break)
//  - residual/STE updates in reference f32 op order
//
// ROUND-14 STRUCTURE: the allocator refuses >64 VGPRs (r7/8/13 all pinned at
// 64 and spilled r[64] to scratch; hints ignored). So make the kernel FIT:
// residual lives in LDS (stride 65 -> (lane+d)%32 banks, 2-way = free),
// re-read in 4-float chunks during scoring (chain order preserved -> bit
// identical). 4 waves/block share one 64-row group: wave w scans centroids
// [w*256,(w+1)*256); LDS argmin combine; wave 0 owns update + outputs.
// Grid 2048 blocks -> 32 waves/CU (100% occupancy cap), no scratch.

#define RQ_K 4
#define RQ_C 1024
#define RQ_D 64
#define RQ_N 131072
#define RSTR 65  // LDS row stride (floats): bank = (lane + d) % 32 -> 2-way

// ---------------- kernel 0: centroid norms, numpy pairwise-8 order ----------------
__global__ void rq_cnorm_kernel(const float* __restrict__ cb,
                                float* __restrict__ cn32) {
  int c = blockIdx.x * blockDim.x + threadIdx.x;
  if (c >= RQ_K * RQ_C) return;
  const float* p = cb + (size_t)c * RQ_D;
  float rr[8];
#pragma unroll
  for (int j = 0; j < 8; ++j) {
    float sq = p[j] * p[j];
    asm volatile("" : "+v"(sq));  // forbid fma contraction: square rounds alone
    rr[j] = sq;
  }
#pragma unroll
  for (int i = 8; i < RQ_D; i += 8) {
#pragma unroll
    for (int j = 0; j < 8; ++j) {
      float sq = p[i + j] * p[i + j];
      asm volatile("" : "+v"(sq));
      rr[j] = rr[j] + sq;
    }
  }
  float s = ((rr[0] + rr[1]) + (rr[2] + rr[3])) + ((rr[4] + rr[5]) + (rr[6] + rr[7]));
  cn32[c] = s;
}

// ---------------- kernel 1: main RQ ----------------
__launch_bounds__(256)
__global__ void rq_main_kernel(const float* __restrict__ in,
                               const float* __restrict__ cb,
                               const float* __restrict__ cn32,
                               float* __restrict__ out_q,
                               float* __restrict__ out_nn,
                               float* __restrict__ out_counts,
                               double* __restrict__ ssq_acc) {
  const int wave = __builtin_amdgcn_readfirstlane(threadIdx.x >> 6);  // SGPR
  const int lane = threadIdx.x & 63;
  const int row  = blockIdx.x * 64 + lane;   // all 4 waves share these 64 rows

  __shared__ float r_lds[64 * RSTR];  // residual, one row per lane slot
  __shared__ float lmv[4][64];
  __shared__ int   lmi[4][64];

  // wave 0 stages the input rows into LDS
  if (wave == 0) {
    const float4* ip = reinterpret_cast<const float4*>(in + (size_t)row * RQ_D);
#pragma unroll
    for (int i = 0; i < RQ_D / 4; ++i) {
      float4 v = ip[i];
      r_lds[lane * RSTR + 4 * i + 0] = v.x;
      r_lds[lane * RSTR + 4 * i + 1] = v.y;
      r_lds[lane * RSTR + 4 * i + 2] = v.z;
      r_lds[lane * RSTR + 4 * i + 3] = v.w;
    }
  }
  __syncthreads();

  double ssq = 0.0;  // loss partial (wave 0 only)

#pragma unroll 1
  for (int k = 0; k < RQ_K; ++k) {
    const float* cbk = cb + (size_t)k * RQ_C * RQ_D;
    const float* cnk = cn32 + k * RQ_C;
    const int c0 = __builtin_amdgcn_readfirstlane(wave * (RQ_C / 4));
    float m1 = 3.402823466e38f;
    int i1 = c0;

    // screening over this wave's 256 centroids, 4 per iteration.
    // c uniform -> codebook/cn stay scalar loads (SGPR path, r4/r10 lesson).
    // residual re-read from LDS in 4-float chunks; per-centroid FMA chain
    // remains d-ascending -> scores bit-identical to the reference.
#pragma unroll 1
    for (int c = c0; c < c0 + RQ_C / 4; c += 4) {
      const float* bp = cbk + (size_t)c * RQ_D;
      float a0 = 0.f, a1 = 0.f, a2 = 0.f, a3 = 0.f;
#pragma unroll
      for (int i = 0; i < RQ_D / 4; ++i) {
        const float r0 = r_lds[lane * RSTR + 4 * i + 0];
        const float r1 = r_lds[lane * RSTR + 4 * i + 1];
        const float r2 = r_lds[lane * RSTR + 4 * i + 2];
        const float r3 = r_lds[lane * RSTR + 4 * i + 3];
        float4 v0 = *reinterpret_cast<const float4*>(bp + 4 * i);
        a0 = fmaf(v0.x, r0, a0);
        a0 = fmaf(v0.y, r1, a0);
        a0 = fmaf(v0.z, r2, a0);
        a0 = fmaf(v0.w, r3, a0);
        float4 v1 = *reinterpret_cast<const float4*>(bp + RQ_D + 4 * i);
        a1 = fmaf(v1.x, r0, a1);
        a1 = fmaf(v1.y, r1, a1);
        a1 = fmaf(v1.z, r2, a1);
        a1 = fmaf(v1.w, r3, a1);
        float4 v2 = *reinterpret_cast<const float4*>(bp + 2 * RQ_D + 4 * i);
        a2 = fmaf(v2.x, r0, a2);
        a2 = fmaf(v2.y, r1, a2);
        a2 = fmaf(v2.z, r2, a2);
        a2 = fmaf(v2.w, r3, a2);
        float4 v3 = *reinterpret_cast<const float4*>(bp + 3 * RQ_D + 4 * i);
        a3 = fmaf(v3.x, r0, a3);
        a3 = fmaf(v3.y, r1, a3);
        a3 = fmaf(v3.z, r2, a3);
        a3 = fmaf(v3.w, r3, a3);
      }
      float s0 = fmaf(-2.f, a0, cnk[c + 0]);
      float s1 = fmaf(-2.f, a1, cnk[c + 1]);
      float s2 = fmaf(-2.f, a2, cnk[c + 2]);
      float s3 = fmaf(-2.f, a3, cnk[c + 3]);
      bool l0 = s0 < m1; m1 = l0 ? s0 : m1; i1 = l0 ? (c + 0) : i1;
      bool l1 = s1 < m1; m1 = l1 ? s1 : m1; i1 = l1 ? (c + 1) : i1;
      bool l2 = s2 < m1; m1 = l2 ? s2 : m1; i1 = l2 ? (c + 2) : i1;
      bool l3 = s3 < m1; m1 = l3 ? s3 : m1; i1 = l3 ? (c + 3) : i1;
    }

    // 4-way argmin combine; ascending partition + strict < = first occurrence
    lmv[wave][lane] = m1;
    lmi[wave][lane] = i1;
    __syncthreads();
    float bm = lmv[0][lane];
    int   bi = lmi[0][lane];
#pragma unroll
    for (int p = 1; p < 4; ++p) {
      float pm = lmv[p][lane];
      int   pi = lmi[p][lane];
      bool lt = pm < bm;
      bm = lt ? pm : bm;
      bi = lt ? pi : bi;
    }
    const int best = bi;

    // wave 0: outputs + residual/STE update in LDS (reference f32 op order)
    if (wave == 0) {
      out_nn[k * RQ_N + row] = (float)best;
      atomicAdd(&out_counts[k * RQ_C + best], 1.0f);
      const float4* qp = reinterpret_cast<const float4*>(cbk + (size_t)best * RQ_D);
#pragma unroll
      for (int i = 0; i < RQ_D / 4; ++i) {
        float4 qv = qp[i];
        float qa[4] = {qv.x, qv.y, qv.z, qv.w};
#pragma unroll
        for (int j = 0; j < 4; ++j) {
          int d = 4 * i + j;
          float rd = r_lds[lane * RSTR + d];
          float t = qa[j] - rd;   // quant - residual
          float qste = rd + t;    // straight-through value
          rd = rd - qste;         // new residual
          r_lds[lane * RSTR + d] = rd;
          ssq = fma((double)t, (double)t, ssq);
        }
      }
    }
    __syncthreads();  // updated residual visible to all waves; lmv reusable
  }

  // quantized = in_row - r_final (telescoped quant_ste sum; ~1 ulp from np's
  // pairwise 4-term sum, far inside threshold)
  if (wave == 0) {
    const float4* ip = reinterpret_cast<const float4*>(in + (size_t)row * RQ_D);
    float4* op = reinterpret_cast<float4*>(out_q + (size_t)row * RQ_D);
#pragma unroll
    for (int i = 0; i < RQ_D / 4; ++i) {
      float4 v = ip[i];
      op[i] = make_float4(v.x - r_lds[lane * RSTR + 4 * i + 0],
                          v.y - r_lds[lane * RSTR + 4 * i + 1],
                          v.z - r_lds[lane * RSTR + 4 * i + 2],
                          v.w - r_lds[lane * RSTR + 4 * i + 3]);
    }
    // wave-level loss reduction, one atomic per block
#pragma unroll
    for (int off = 32; off > 0; off >>= 1) ssq += __shfl_down(ssq, off);
    if (lane == 0) atomicAdd(ssq_acc, ssq);
  }
}

// ---------------- kernel 2: loss broadcast + codebook copy ----------------
__global__ void rq_final_kernel(const double* __restrict__ ssq_acc,
                                const float* __restrict__ cb,
                                float* __restrict__ out_loss,
                                float* __restrict__ out_cb) {
  int i = blockIdx.x * blockDim.x + threadIdx.x;
  float lossf = (float)(ssq_acc[0] / (double)((long long)RQ_N * RQ_D));
  if (i < RQ_N) out_loss[i] = lossf;
  if (i < RQ_K * RQ_C * RQ_D) out_cb[i] = cb[i];
}

extern "C" void kernel_launch(void* const* d_in, const int* in_sizes, int n_in,
                              void* d_out, int out_size, void* d_ws, size_t ws_size,
                              hipStream_t stream) {
  const float* in = (const float*)d_in[0];
  const float* cb = (const float*)d_in[1];
  float* out = (float*)d_out;

  float* out_q      = out;                       // 8388608
  float* out_loss   = out + 8388608;             // 131072
  float* out_nn     = out + 8519680;             // 524288
  float* out_cb     = out + 9043968;             // 262144
  float* out_counts = out + 9306112;             // 4096  (total 9310208)

  double* ws_ssq = (double*)d_ws;
  float*  cn32   = (float*)((char*)d_ws + 16);

  hipMemsetAsync(d_ws, 0, 16, stream);
  hipMemsetAsync(out_counts, 0, RQ_K * RQ_C * sizeof(float), stream);

  rq_cnorm_kernel<<<(RQ_K * RQ_C) / 256, 256, 0, stream>>>(cb, cn32);
  rq_main_kernel<<<RQ_N / 64, 256, 0, stream>>>(in, cb, cn32,
                                                out_q, out_nn, out_counts, ws_ssq);
  rq_final_kernel<<<(RQ_K * RQ_C * RQ_D) / 256, 256, 0, stream>>>(ws_ssq, cb,
                                                                  out_loss, out_cb);
}

// Round 15
// 1247.419 us; speedup vs baseline: 3.4968x; 1.0560x over previous
//
#include <hip/hip_runtime.h>

// ResidualQuantizer: K=4 stages, C=1024 centroids, D=64, N=B*T=131072 rows.
// Outputs (flat f32 concat): quantized[N*D], loss[N], nn_idx[K*N] (as float),
// codebooks_out[K*C*D], counts[K*C].
//
// Bit-matches the checker's numpy-f32 reference pipeline:
//  - dot(residual, centroid): sequential d-ascending f32 FMA chain per centroid
//  - ||c||^2: numpy pairwise-8 sum of separately-rounded squares
//  - score = fmaf(-2, dot, cn)
//  - argmin: first strict min, ascending c (ascending-partition tie-break)
//  - residual/STE updates in reference f32 op order
//
// Structure (r14, kept): residual in LDS (allocator refuses >64 VGPRs; r[64]
// in registers always spilled). 4 waves/block share one 64-row group; wave w
// scans centroids [w*256,(w+1)*256); LDS argmin combine; wave 0 owns updates.
// Grid 2048 blocks. VGPR=48, zero scratch, VALUBusy 85%.
//
// r15: 8-centroid groups (8 indep FMA chains, halves select/score overhead
// per FMA) + RSTR 66 so residual re-reads are 8B-aligned float2 (ds_read_b64,
// halves LDS instruction count; 4-way bank alias costs only the subordinate
// LDS pipe 1.58x per m136).

#define RQ_K 4
#define RQ_C 1024
#define RQ_D 64
#define RQ_N 131072
#define RSTR 66  // floats; lane*66*4 B = 8B-aligned -> b64 reads; 4-way alias

// ---------------- kernel 0: centroid norms, numpy pairwise-8 order ----------------
__global__ void rq_cnorm_kernel(const float* __restrict__ cb,
                                float* __restrict__ cn32) {
  int c = blockIdx.x * blockDim.x + threadIdx.x;
  if (c >= RQ_K * RQ_C) return;
  const float* p = cb + (size_t)c * RQ_D;
  float rr[8];
#pragma unroll
  for (int j = 0; j < 8; ++j) {
    float sq = p[j] * p[j];
    asm volatile("" : "+v"(sq));  // forbid fma contraction: square rounds alone
    rr[j] = sq;
  }
#pragma unroll
  for (int i = 8; i < RQ_D; i += 8) {
#pragma unroll
    for (int j = 0; j < 8; ++j) {
      float sq = p[i + j] * p[i + j];
      asm volatile("" : "+v"(sq));
      rr[j] = rr[j] + sq;
    }
  }
  float s = ((rr[0] + rr[1]) + (rr[2] + rr[3])) + ((rr[4] + rr[5]) + (rr[6] + rr[7]));
  cn32[c] = s;
}

// ---------------- kernel 1: main RQ ----------------
__launch_bounds__(256)
__global__ void rq_main_kernel(const float* __restrict__ in,
                               const float* __restrict__ cb,
                               const float* __restrict__ cn32,
                               float* __restrict__ out_q,
                               float* __restrict__ out_nn,
                               float* __restrict__ out_counts,
                               double* __restrict__ ssq_acc) {
  const int wave = __builtin_amdgcn_readfirstlane(threadIdx.x >> 6);  // SGPR
  const int lane = threadIdx.x & 63;
  const int row  = blockIdx.x * 64 + lane;   // all 4 waves share these 64 rows

  __shared__ float r_lds[64 * RSTR];  // residual, one row per lane slot
  __shared__ float lmv[4][64];
  __shared__ int   lmi[4][64];

  // wave 0 stages the input rows into LDS
  if (wave == 0) {
    const float4* ip = reinterpret_cast<const float4*>(in + (size_t)row * RQ_D);
#pragma unroll
    for (int i = 0; i < RQ_D / 4; ++i) {
      float4 v = ip[i];
      r_lds[lane * RSTR + 4 * i + 0] = v.x;
      r_lds[lane * RSTR + 4 * i + 1] = v.y;
      r_lds[lane * RSTR + 4 * i + 2] = v.z;
      r_lds[lane * RSTR + 4 * i + 3] = v.w;
    }
  }
  __syncthreads();

  double ssq = 0.0;  // loss partial (wave 0 only)

#pragma unroll 1
  for (int k = 0; k < RQ_K; ++k) {
    const float* cbk = cb + (size_t)k * RQ_C * RQ_D;
    const float* cnk = cn32 + k * RQ_C;
    const int c0 = __builtin_amdgcn_readfirstlane(wave * (RQ_C / 4));
    float m1 = 3.402823466e38f;
    int i1 = c0;

    // screening over this wave's 256 centroids, 8 per iteration (8 indep
    // chains, each d-ascending -> bit-identical scores). c uniform ->
    // codebook/cn stay scalar loads. Residual re-read from LDS as float2.
#pragma unroll 1
    for (int c = c0; c < c0 + RQ_C / 4; c += 8) {
      const float* bp = cbk + (size_t)c * RQ_D;
      float a0 = 0.f, a1 = 0.f, a2 = 0.f, a3 = 0.f;
      float a4 = 0.f, a5 = 0.f, a6 = 0.f, a7 = 0.f;
#pragma unroll
      for (int i = 0; i < RQ_D / 4; ++i) {
        const float2 rlo = *reinterpret_cast<const float2*>(&r_lds[lane * RSTR + 4 * i + 0]);
        const float2 rhi = *reinterpret_cast<const float2*>(&r_lds[lane * RSTR + 4 * i + 2]);
        const float r0 = rlo.x, r1 = rlo.y, r2 = rhi.x, r3 = rhi.y;
        float4 v0 = *reinterpret_cast<const float4*>(bp + 0 * RQ_D + 4 * i);
        a0 = fmaf(v0.x, r0, a0); a0 = fmaf(v0.y, r1, a0);
        a0 = fmaf(v0.z, r2, a0); a0 = fmaf(v0.w, r3, a0);
        float4 v1 = *reinterpret_cast<const float4*>(bp + 1 * RQ_D + 4 * i);
        a1 = fmaf(v1.x, r0, a1); a1 = fmaf(v1.y, r1, a1);
        a1 = fmaf(v1.z, r2, a1); a1 = fmaf(v1.w, r3, a1);
        float4 v2 = *reinterpret_cast<const float4*>(bp + 2 * RQ_D + 4 * i);
        a2 = fmaf(v2.x, r0, a2); a2 = fmaf(v2.y, r1, a2);
        a2 = fmaf(v2.z, r2, a2); a2 = fmaf(v2.w, r3, a2);
        float4 v3 = *reinterpret_cast<const float4*>(bp + 3 * RQ_D + 4 * i);
        a3 = fmaf(v3.x, r0, a3); a3 = fmaf(v3.y, r1, a3);
        a3 = fmaf(v3.z, r2, a3); a3 = fmaf(v3.w, r3, a3);
        float4 v4 = *reinterpret_cast<const float4*>(bp + 4 * RQ_D + 4 * i);
        a4 = fmaf(v4.x, r0, a4); a4 = fmaf(v4.y, r1, a4);
        a4 = fmaf(v4.z, r2, a4); a4 = fmaf(v4.w, r3, a4);
        float4 v5 = *reinterpret_cast<const float4*>(bp + 5 * RQ_D + 4 * i);
        a5 = fmaf(v5.x, r0, a5); a5 = fmaf(v5.y, r1, a5);
        a5 = fmaf(v5.z, r2, a5); a5 = fmaf(v5.w, r3, a5);
        float4 v6 = *reinterpret_cast<const float4*>(bp + 6 * RQ_D + 4 * i);
        a6 = fmaf(v6.x, r0, a6); a6 = fmaf(v6.y, r1, a6);
        a6 = fmaf(v6.z, r2, a6); a6 = fmaf(v6.w, r3, a6);
        float4 v7 = *reinterpret_cast<const float4*>(bp + 7 * RQ_D + 4 * i);
        a7 = fmaf(v7.x, r0, a7); a7 = fmaf(v7.y, r1, a7);
        a7 = fmaf(v7.z, r2, a7); a7 = fmaf(v7.w, r3, a7);
      }
      float s0 = fmaf(-2.f, a0, cnk[c + 0]);
      float s1 = fmaf(-2.f, a1, cnk[c + 1]);
      float s2 = fmaf(-2.f, a2, cnk[c + 2]);
      float s3 = fmaf(-2.f, a3, cnk[c + 3]);
      float s4 = fmaf(-2.f, a4, cnk[c + 4]);
      float s5 = fmaf(-2.f, a5, cnk[c + 5]);
      float s6 = fmaf(-2.f, a6, cnk[c + 6]);
      float s7 = fmaf(-2.f, a7, cnk[c + 7]);
      // first-strict-min in ascending c order (numpy argmin semantics)
      bool l0 = s0 < m1; m1 = l0 ? s0 : m1; i1 = l0 ? (c + 0) : i1;
      bool l1 = s1 < m1; m1 = l1 ? s1 : m1; i1 = l1 ? (c + 1) : i1;
      bool l2 = s2 < m1; m1 = l2 ? s2 : m1; i1 = l2 ? (c + 2) : i1;
      bool l3 = s3 < m1; m1 = l3 ? s3 : m1; i1 = l3 ? (c + 3) : i1;
      bool l4 = s4 < m1; m1 = l4 ? s4 : m1; i1 = l4 ? (c + 4) : i1;
      bool l5 = s5 < m1; m1 = l5 ? s5 : m1; i1 = l5 ? (c + 5) : i1;
      bool l6 = s6 < m1; m1 = l6 ? s6 : m1; i1 = l6 ? (c + 6) : i1;
      bool l7 = s7 < m1; m1 = l7 ? s7 : m1; i1 = l7 ? (c + 7) : i1;
    }

    // 4-way argmin combine; ascending partition + strict < = first occurrence
    lmv[wave][lane] = m1;
    lmi[wave][lane] = i1;
    __syncthreads();
    float bm = lmv[0][lane];
    int   bi = lmi[0][lane];
#pragma unroll
    for (int p = 1; p < 4; ++p) {
      float pm = lmv[p][lane];
      int   pi = lmi[p][lane];
      bool lt = pm < bm;
      bm = lt ? pm : bm;
      bi = lt ? pi : bi;
    }
    const int best = bi;

    // wave 0: outputs + residual/STE update in LDS (reference f32 op order)
    if (wave == 0) {
      out_nn[k * RQ_N + row] = (float)best;
      atomicAdd(&out_counts[k * RQ_C + best], 1.0f);
      const float4* qp = reinterpret_cast<const float4*>(cbk + (size_t)best * RQ_D);
#pragma unroll
      for (int i = 0; i < RQ_D / 4; ++i) {
        float4 qv = qp[i];
        float qa[4] = {qv.x, qv.y, qv.z, qv.w};
#pragma unroll
        for (int j = 0; j < 4; ++j) {
          int d = 4 * i + j;
          float rd = r_lds[lane * RSTR + d];
          float t = qa[j] - rd;   // quant - residual
          float qste = rd + t;    // straight-through value
          rd = rd - qste;         // new residual
          r_lds[lane * RSTR + d] = rd;
          ssq = fma((double)t, (double)t, ssq);
        }
      }
    }
    __syncthreads();  // updated residual visible to all waves; lmv reusable
  }

  // quantized = in_row - r_final (telescoped quant_ste sum; ~1 ulp from np's
  // pairwise 4-term sum, far inside threshold)
  if (wave == 0) {
    const float4* ip = reinterpret_cast<const float4*>(in + (size_t)row * RQ_D);
    float4* op = reinterpret_cast<float4*>(out_q + (size_t)row * RQ_D);
#pragma unroll
    for (int i = 0; i < RQ_D / 4; ++i) {
      float4 v = ip[i];
      op[i] = make_float4(v.x - r_lds[lane * RSTR + 4 * i + 0],
                          v.y - r_lds[lane * RSTR + 4 * i + 1],
                          v.z - r_lds[lane * RSTR + 4 * i + 2],
                          v.w - r_lds[lane * RSTR + 4 * i + 3]);
    }
    // wave-level loss reduction, one atomic per block
#pragma unroll
    for (int off = 32; off > 0; off >>= 1) ssq += __shfl_down(ssq, off);
    if (lane == 0) atomicAdd(ssq_acc, ssq);
  }
}

// ---------------- kernel 2: loss broadcast + codebook copy ----------------
__global__ void rq_final_kernel(const double* __restrict__ ssq_acc,
                                const float* __restrict__ cb,
                                float* __restrict__ out_loss,
                                float* __restrict__ out_cb) {
  int i = blockIdx.x * blockDim.x + threadIdx.x;
  float lossf = (float)(ssq_acc[0] / (double)((long long)RQ_N * RQ_D));
  if (i < RQ_N) out_loss[i] = lossf;
  if (i < RQ_K * RQ_C * RQ_D) out_cb[i] = cb[i];
}

extern "C" void kernel_launch(void* const* d_in, const int* in_sizes, int n_in,
                              void* d_out, int out_size, void* d_ws, size_t ws_size,
                              hipStream_t stream) {
  const float* in = (const float*)d_in[0];
  const float* cb = (const float*)d_in[1];
  float* out = (float*)d_out;

  float* out_q      = out;                       // 8388608
  float* out_loss   = out + 8388608;             // 131072
  float* out_nn     = out + 8519680;             // 524288
  float* out_cb     = out + 9043968;             // 262144
  float* out_counts = out + 9306112;             // 4096  (total 9310208)

  double* ws_ssq = (double*)d_ws;
  float*  cn32   = (float*)((char*)d_ws + 16);

  hipMemsetAsync(d_ws, 0, 16, stream);
  hipMemsetAsync(out_counts, 0, RQ_K * RQ_C * sizeof(float), stream);

  rq_cnorm_kernel<<<(RQ_K * RQ_C) / 256, 256, 0, stream>>>(cb, cn32);
  rq_main_kernel<<<RQ_N / 64, 256, 0, stream>>>(in, cb, cn32,
                                                out_q, out_nn, out_counts, ws_ssq);
  rq_final_kernel<<<(RQ_K * RQ_C * RQ_D) / 256, 256, 0, stream>>>(ws_ssq, cb,
                                                                  out_loss, out_cb);
}

// Round 16
// 599.519 us; speedup vs baseline: 7.2758x; 2.0807x over previous
//
#include <hip/hip_runtime.h>
#include <hip/hip_bf16.h>

// ResidualQuantizer: K=4 stages, C=1024 centroids, D=64, N=B*T=131072 rows.
// r16: bf16-MFMA screening + exact-f32 rescore of a provably-containing
// window. Argmin/residual/STE remain bit-matched to the numpy-f32 pipeline.
//
//  - screen: S ~ -2*(R_bf16 CB_bf16^T) + cn via mfma_f32_16x16x32_bf16
//    |screen - exact| <= ~0.7 worst case (2*2^-8 rel/term, sum|rc|<~80)
//  - pass A: per-row screen min. pass B: admit all c with s < min + W (W=3)
//    into per-row candidate list (true f32-argmin provably admitted).
//  - exact rescore of candidates with the reference d-ascending f32 chain,
//    lex-min (score, index) == np first-occurrence argmin semantics.

#define RQ_K 4
#define RQ_C 1024
#define RQ_D 64
#define RQ_N 131072
#define RSTR 66    // f32 residual LDS stride (floats)
#define BSTR 72    // bf16 residual LDS stride (=144B rows -> 2-way banks on A reads)
#define WWIN 3.0f  // screen window, >= 4x worst-case screen error
#define CCAP 96    // candidate capacity per row

typedef __attribute__((ext_vector_type(8))) short s16x8;
typedef __attribute__((ext_vector_type(4))) float f32x4;

static __device__ inline unsigned short f2bf(float x) {
  __hip_bfloat16 h = __float2bfloat16(x);  // RNE
  return *reinterpret_cast<unsigned short*>(&h);
}

// ---------------- kernel 0: centroid norms, numpy pairwise-8 order ----------------
__global__ void rq_cnorm_kernel(const float* __restrict__ cb,
                                float* __restrict__ cn32) {
  int c = blockIdx.x * blockDim.x + threadIdx.x;
  if (c >= RQ_K * RQ_C) return;
  const float* p = cb + (size_t)c * RQ_D;
  float rr[8];
#pragma unroll
  for (int j = 0; j < 8; ++j) {
    float sq = p[j] * p[j];
    asm volatile("" : "+v"(sq));  // square rounds alone (no fma contraction)
    rr[j] = sq;
  }
#pragma unroll
  for (int i = 8; i < RQ_D; i += 8) {
#pragma unroll
    for (int j = 0; j < 8; ++j) {
      float sq = p[i + j] * p[i + j];
      asm volatile("" : "+v"(sq));
      rr[j] = rr[j] + sq;
    }
  }
  cn32[c] = ((rr[0] + rr[1]) + (rr[2] + rr[3])) + ((rr[4] + rr[5]) + (rr[6] + rr[7]));
}

// ---------------- kernel 0b: f32 -> bf16 codebook ----------------
__global__ void rq_cvt_kernel(const float* __restrict__ cb,
                              unsigned short* __restrict__ cbh) {
  int i = blockIdx.x * 256 + threadIdx.x;
  cbh[i] = f2bf(cb[i]);
}

// ---------------- kernel 1: main RQ ----------------
__launch_bounds__(256)
__global__ void rq_main_kernel(const float* __restrict__ in,
                               const float* __restrict__ cb,
                               const unsigned short* __restrict__ cbh,
                               const float* __restrict__ cn32,
                               float* __restrict__ out_q,
                               float* __restrict__ out_nn,
                               float* __restrict__ out_counts,
                               double* __restrict__ ssq_acc) {
  const int wave = __builtin_amdgcn_readfirstlane(threadIdx.x >> 6);
  const int lane = threadIdx.x & 63;
  const int l15 = lane & 15;
  const int l4  = lane >> 4;
  const int rowbase = blockIdx.x * 64;

  __shared__ float r_f32[64 * RSTR];
  __shared__ unsigned short r_bf[64 * BSTR];
  __shared__ float m_part[4][64];
  __shared__ float m_row[64];
  __shared__ int   cnt[64];
  __shared__ unsigned short cand[64][CCAP];
  __shared__ float pv[4][64];
  __shared__ int   pi[4][64];
  __shared__ int   best_idx[64];

  // init: stage input rows into LDS (f32 + bf16). thread t: row=t>>2, 16 elems
  {
    int row = threadIdx.x >> 2, q = threadIdx.x & 3;
    const float4* ip =
        reinterpret_cast<const float4*>(in + (size_t)(rowbase + row) * RQ_D + q * 16);
#pragma unroll
    for (int u = 0; u < 4; ++u) {
      float4 v = ip[u];
      int d = q * 16 + u * 4;
      r_f32[row * RSTR + d + 0] = v.x; r_bf[row * BSTR + d + 0] = f2bf(v.x);
      r_f32[row * RSTR + d + 1] = v.y; r_bf[row * BSTR + d + 1] = f2bf(v.y);
      r_f32[row * RSTR + d + 2] = v.z; r_bf[row * BSTR + d + 2] = f2bf(v.z);
      r_f32[row * RSTR + d + 3] = v.w; r_bf[row * BSTR + d + 3] = f2bf(v.w);
    }
  }
  __syncthreads();

  double ssq = 0.0;

#pragma unroll 1
  for (int k = 0; k < RQ_K; ++k) {
    const unsigned short* cbhk = cbh + (size_t)k * RQ_C * RQ_D;
    const float* cbk = cb + (size_t)k * RQ_C * RQ_D;
    const float* cnk = cn32 + k * RQ_C;
    const int cbase = __builtin_amdgcn_readfirstlane(wave * 256);

    // ---- PASS A: per-row screen min over this wave's 256 cols ----
    float rm[4][4];
#pragma unroll
    for (int rt = 0; rt < 4; ++rt)
#pragma unroll
      for (int reg = 0; reg < 4; ++reg) rm[rt][reg] = 3.402823466e38f;

#pragma unroll 1
    for (int ct = 0; ct < 16; ++ct) {
      const int ccol = cbase + ct * 16 + l15;
      s16x8 b0 = *reinterpret_cast<const s16x8*>(cbhk + (size_t)ccol * RQ_D + l4 * 8);
      s16x8 b1 = *reinterpret_cast<const s16x8*>(cbhk + (size_t)ccol * RQ_D + 32 + l4 * 8);
      float cnl = cnk[ccol];
#pragma unroll
      for (int rt = 0; rt < 4; ++rt) {
        s16x8 a0 = *reinterpret_cast<const s16x8*>(&r_bf[(rt * 16 + l15) * BSTR + l4 * 8]);
        s16x8 a1 = *reinterpret_cast<const s16x8*>(&r_bf[(rt * 16 + l15) * BSTR + 32 + l4 * 8]);
        f32x4 acc = {0.f, 0.f, 0.f, 0.f};
        acc = __builtin_amdgcn_mfma_f32_16x16x32_bf16(a0, b0, acc, 0, 0, 0);
        acc = __builtin_amdgcn_mfma_f32_16x16x32_bf16(a1, b1, acc, 0, 0, 0);
#pragma unroll
        for (int reg = 0; reg < 4; ++reg) {
          float s = fmaf(-2.f, acc[reg], cnl);
          rm[rt][reg] = fminf(rm[rt][reg], s);
        }
      }
    }
    // reduce across the 16 col-lanes (same row lives in lanes differing in bits0-3)
#pragma unroll
    for (int rt = 0; rt < 4; ++rt)
#pragma unroll
      for (int reg = 0; reg < 4; ++reg) {
        float v = rm[rt][reg];
        v = fminf(v, __shfl_xor(v, 1));
        v = fminf(v, __shfl_xor(v, 2));
        v = fminf(v, __shfl_xor(v, 4));
        v = fminf(v, __shfl_xor(v, 8));
        rm[rt][reg] = v;
      }
    if (l15 == 0) {
#pragma unroll
      for (int rt = 0; rt < 4; ++rt)
#pragma unroll
        for (int reg = 0; reg < 4; ++reg)
          m_part[wave][rt * 16 + l4 * 4 + reg] = rm[rt][reg];
    }
    __syncthreads();
    if (wave == 0)
      m_row[lane] = fminf(fminf(m_part[0][lane], m_part[1][lane]),
                          fminf(m_part[2][lane], m_part[3][lane]));
    if (wave == 1) cnt[lane] = 0;
    pv[wave][lane] = 3.402823466e38f;
    pi[wave][lane] = 0x7FFFFFFF;
    __syncthreads();

    // per-lane admission thresholds for the 16 rows this lane covers
    float thr[4][4];
#pragma unroll
    for (int rt = 0; rt < 4; ++rt)
#pragma unroll
      for (int reg = 0; reg < 4; ++reg)
        thr[rt][reg] = m_row[rt * 16 + l4 * 4 + reg] + WWIN;

    // ---- PASS B: admit window members ----
#pragma unroll 1
    for (int ct = 0; ct < 16; ++ct) {
      const int ccol = cbase + ct * 16 + l15;
      s16x8 b0 = *reinterpret_cast<const s16x8*>(cbhk + (size_t)ccol * RQ_D + l4 * 8);
      s16x8 b1 = *reinterpret_cast<const s16x8*>(cbhk + (size_t)ccol * RQ_D + 32 + l4 * 8);
      float cnl = cnk[ccol];
#pragma unroll
      for (int rt = 0; rt < 4; ++rt) {
        s16x8 a0 = *reinterpret_cast<const s16x8*>(&r_bf[(rt * 16 + l15) * BSTR + l4 * 8]);
        s16x8 a1 = *reinterpret_cast<const s16x8*>(&r_bf[(rt * 16 + l15) * BSTR + 32 + l4 * 8]);
        f32x4 acc = {0.f, 0.f, 0.f, 0.f};
        acc = __builtin_amdgcn_mfma_f32_16x16x32_bf16(a0, b0, acc, 0, 0, 0);
        acc = __builtin_amdgcn_mfma_f32_16x16x32_bf16(a1, b1, acc, 0, 0, 0);
#pragma unroll
        for (int reg = 0; reg < 4; ++reg) {
          float s = fmaf(-2.f, acc[reg], cnl);
          if (s < thr[rt][reg]) {
            int row = rt * 16 + l4 * 4 + reg;
            int slot = atomicAdd(&cnt[row], 1);
            if (slot < CCAP) cand[row][slot] = (unsigned short)ccol;
          }
        }
      }
    }
    __syncthreads();

    // ---- exact f32 rescore of candidates (reference chain, lex-min) ----
    {
      int row = threadIdx.x & 63;
      int j0  = threadIdx.x >> 6;
      int n = cnt[row]; n = n > CCAP ? CCAP : n;
      float bs = 3.402823466e38f;
      int bc = 0x7FFFFFFF;
      for (int j = j0; j < n; j += 4) {
        int c = cand[row][j];
        const float* cp = cbk + (size_t)c * RQ_D;
        float a = 0.f;
#pragma unroll
        for (int d = 0; d < RQ_D; ++d) a = fmaf(cp[d], r_f32[row * RSTR + d], a);
        float s = fmaf(-2.f, a, cnk[c]);
        if (s < bs || (s == bs && c < bc)) { bs = s; bc = c; }
      }
      pv[j0][row] = bs;
      pi[j0][row] = bc;
    }
    __syncthreads();
    if (threadIdx.x < 64) {
      int row = threadIdx.x;
      float bs = pv[0][row]; int bc = pi[0][row];
#pragma unroll
      for (int p = 1; p < 4; ++p) {
        float s2 = pv[p][row]; int c2 = pi[p][row];
        if (s2 < bs || (s2 == bs && c2 < bc)) { bs = s2; bc = c2; }
      }
      best_idx[row] = (bc == 0x7FFFFFFF) ? 0 : bc;  // safety (n==0 impossible)
    }
    __syncthreads();

    // ---- outputs + residual/STE update (wave 0, lane = row) ----
    if (wave == 0) {
      int best = best_idx[lane];
      out_nn[k * RQ_N + rowbase + lane] = (float)best;
      atomicAdd(&out_counts[k * RQ_C + best], 1.0f);
      const float4* qp = reinterpret_cast<const float4*>(cbk + (size_t)best * RQ_D);
#pragma unroll
      for (int i = 0; i < RQ_D / 4; ++i) {
        float4 qv = qp[i];
        float qa[4] = {qv.x, qv.y, qv.z, qv.w};
#pragma unroll
        for (int j = 0; j < 4; ++j) {
          int d = 4 * i + j;
          float rd = r_f32[lane * RSTR + d];
          float t = qa[j] - rd;   // quant - residual
          float qste = rd + t;    // straight-through value
          rd = rd - qste;         // new residual
          r_f32[lane * RSTR + d] = rd;
          ssq = fma((double)t, (double)t, ssq);
        }
      }
    }
    __syncthreads();
    if (k < RQ_K - 1) {  // refresh bf16 residual for next stage
      int row = threadIdx.x >> 2, q = threadIdx.x & 3;
#pragma unroll
      for (int u = 0; u < 16; ++u) {
        int d = q * 16 + u;
        r_bf[row * BSTR + d] = f2bf(r_f32[row * RSTR + d]);
      }
      __syncthreads();
    }
  }

  // quantized = in - r_final (telescoped; ~1 ulp from np's 4-term sum)
  if (wave == 0) {
    const float4* ip = reinterpret_cast<const float4*>(in + (size_t)(rowbase + lane) * RQ_D);
    float4* op = reinterpret_cast<float4*>(out_q + (size_t)(rowbase + lane) * RQ_D);
#pragma unroll
    for (int i = 0; i < RQ_D / 4; ++i) {
      float4 v = ip[i];
      op[i] = make_float4(v.x - r_f32[lane * RSTR + 4 * i + 0],
                          v.y - r_f32[lane * RSTR + 4 * i + 1],
                          v.z - r_f32[lane * RSTR + 4 * i + 2],
                          v.w - r_f32[lane * RSTR + 4 * i + 3]);
    }
#pragma unroll
    for (int off = 32; off > 0; off >>= 1) ssq += __shfl_down(ssq, off);
    if (lane == 0) atomicAdd(ssq_acc, ssq);
  }
}

// ---------------- kernel 2: loss broadcast + codebook copy ----------------
__global__ void rq_final_kernel(const double* __restrict__ ssq_acc,
                                const float* __restrict__ cb,
                                float* __restrict__ out_loss,
                                float* __restrict__ out_cb) {
  int i = blockIdx.x * blockDim.x + threadIdx.x;
  float lossf = (float)(ssq_acc[0] / (double)((long long)RQ_N * RQ_D));
  if (i < RQ_N) out_loss[i] = lossf;
  if (i < RQ_K * RQ_C * RQ_D) out_cb[i] = cb[i];
}

extern "C" void kernel_launch(void* const* d_in, const int* in_sizes, int n_in,
                              void* d_out, int out_size, void* d_ws, size_t ws_size,
                              hipStream_t stream) {
  const float* in = (const float*)d_in[0];
  const float* cb = (const float*)d_in[1];
  float* out = (float*)d_out;

  float* out_q      = out;                       // 8388608
  float* out_loss   = out + 8388608;             // 131072
  float* out_nn     = out + 8519680;             // 524288
  float* out_cb     = out + 9043968;             // 262144
  float* out_counts = out + 9306112;             // 4096

  double*         ws_ssq = (double*)d_ws;
  float*          cn32   = (float*)((char*)d_ws + 16);
  unsigned short* cbh    = (unsigned short*)((char*)d_ws + 16 + RQ_K * RQ_C * sizeof(float));

  hipMemsetAsync(d_ws, 0, 16, stream);
  hipMemsetAsync(out_counts, 0, RQ_K * RQ_C * sizeof(float), stream);

  rq_cnorm_kernel<<<(RQ_K * RQ_C) / 256, 256, 0, stream>>>(cb, cn32);
  rq_cvt_kernel<<<(RQ_K * RQ_C * RQ_D) / 256, 256, 0, stream>>>(cb, cbh);
  rq_main_kernel<<<RQ_N / 64, 256, 0, stream>>>(in, cb, cbh, cn32,
                                                out_q, out_nn, out_counts, ws_ssq);
  rq_final_kernel<<<(RQ_K * RQ_C * RQ_D) / 256, 256, 0, stream>>>(ws_ssq, cb,
                                                                  out_loss, out_cb);
}